// Round 1
// baseline (370.339 us; speedup 1.0000x reference)
//
#include <hip/hip_runtime.h>
#include <cstdint>
#include <cstddef>

typedef _Float16 half_t;
typedef __attribute__((ext_vector_type(4))) _Float16 half4v;
typedef __attribute__((ext_vector_type(8))) _Float16 half8v;
typedef __attribute__((ext_vector_type(4))) float float4v;

typedef __attribute__((address_space(1))) const void gv_t;
typedef __attribute__((address_space(3))) void lv_t;

__device__ __forceinline__ void lds_cp16(const void* g, void* l) {
  __builtin_amdgcn_global_load_lds((gv_t*)g, (lv_t*)l, 16, 0, 0);
}

// ---------------- convert fp32 -> fp16, vectorized x4 ----------------
__global__ __launch_bounds__(256) void k_cvt(const float* __restrict__ in,
                                             half_t* __restrict__ out) {
  int i = blockIdx.x * 256 + threadIdx.x;
  float4 v = ((const float4*)in)[i];
  half4v h = {(half_t)v.x, (half_t)v.y, (half_t)v.z, (half_t)v.w};
  ((half4v*)out)[i] = h;
}

// ---------- transpose + convert: in[R][C] fp32 -> out[C][R] fp16 ----------
__global__ __launch_bounds__(256) void k_tcvt(const float* __restrict__ in,
                                              half_t* __restrict__ out, int R, int C) {
  __shared__ float t[32][33];
  int c0 = blockIdx.x * 32, r0 = blockIdx.y * 32;
  int tc = threadIdx.x & 31, tr = threadIdx.x >> 5;  // tr 0..7
#pragma unroll
  for (int i = 0; i < 4; i++)
    t[tr + i * 8][tc] = in[(size_t)(r0 + tr + i * 8) * C + c0 + tc];
  __syncthreads();
#pragma unroll
  for (int i = 0; i < 4; i++)
    out[(size_t)(c0 + tr + i * 8) * R + r0 + tc] = (half_t)t[tc][tr + i * 8];
}

// ---------------- 128x128x32 fp16 MFMA GEMM, C = A @ Bt^T ----------------
// A: [M][K] fp16 row-major. Bt: [N][K] fp16 (i.e. B transposed).
// EPI==0: QKV epilogue -> scatter Q[bh][n][hd], K[bh][n][hd], V^T[bh][hd][n], + bias
// EPI==1: fp32 out + bias
template <int EPI>
__global__ __launch_bounds__(256) void k_gemm(
    const half_t* __restrict__ A, const half_t* __restrict__ Bt,
    const float* __restrict__ bias, float* __restrict__ Cout,
    half_t* __restrict__ Qo, half_t* __restrict__ Ko, half_t* __restrict__ Vo,
    int M, int N, int K) {
  __shared__ half_t As[128 * 32];
  __shared__ half_t Bs[128 * 32];
  const int tid = threadIdx.x;
  const int lane = tid & 63;
  const int w = tid >> 6;
  const int m0 = blockIdx.x * 128;
  const int n0 = blockIdx.y * 128;
  const int wr = w >> 1, wc = w & 1;

  // staging mapping: chunk c covers LDS halves [c*512, c*512+512) = 16 rows of 32
  const int c0 = w * 2, c1 = c0 + 1;
  const int sr0 = c0 * 16 + (lane >> 2);
  const int sr1 = c1 * 16 + (lane >> 2);
  const int scol = (lane & 3) * 8;

  const half_t* Ag0 = A + (size_t)(m0 + sr0) * K + scol;
  const half_t* Ag1 = A + (size_t)(m0 + sr1) * K + scol;
  const half_t* Bg0 = Bt + (size_t)(n0 + sr0) * K + scol;
  const half_t* Bg1 = Bt + (size_t)(n0 + sr1) * K + scol;

  float4v acc[4][4] = {};

  const int fr = lane & 15;
  const int fg = lane >> 4;
  const int aoff = (wr * 64 + fr) * 32 + fg * 8;
  const int boff = (wc * 64 + fr) * 32 + fg * 8;

  for (int kt = 0; kt < K; kt += 32) {
    lds_cp16(Ag0 + kt, As + c0 * 512);
    lds_cp16(Ag1 + kt, As + c1 * 512);
    lds_cp16(Bg0 + kt, Bs + c0 * 512);
    lds_cp16(Bg1 + kt, Bs + c1 * 512);
    __syncthreads();
    half8v a[4], b[4];
#pragma unroll
    for (int m = 0; m < 4; m++) a[m] = *(const half8v*)(As + aoff + m * 512);
#pragma unroll
    for (int n = 0; n < 4; n++) b[n] = *(const half8v*)(Bs + boff + n * 512);
#pragma unroll
    for (int m = 0; m < 4; m++)
#pragma unroll
      for (int n = 0; n < 4; n++)
        acc[m][n] = __builtin_amdgcn_mfma_f32_16x16x32_f16(a[m], b[n], acc[m][n], 0, 0, 0);
    __syncthreads();
  }

  const int rq = (lane >> 4) * 4;
  const int cc = lane & 15;
  if constexpr (EPI == 0) {
#pragma unroll
    for (int n = 0; n < 4; n++) {
      int e = n0 + wc * 64 + n * 16 + cc;
      float bv = bias[e];
      int which = e >> 10, h = (e >> 6) & 15, hd = e & 63;
#pragma unroll
      for (int m = 0; m < 4; m++) {
        int rowb = m0 + wr * 64 + m * 16 + rq;
#pragma unroll
        for (int r = 0; r < 4; r++) {
          int row = rowb + r;
          int b_ = row >> 10, tok = row & 1023;
          half_t hv = (half_t)(acc[m][n][r] + bv);
          size_t bh = (size_t)(b_ * 16 + h);
          if (which == 0)
            Qo[(bh * 1024 + tok) * 64 + hd] = hv;
          else if (which == 1)
            Ko[(bh * 1024 + tok) * 64 + hd] = hv;
          else
            Vo[(bh * 64 + hd) * 1024 + tok] = hv;
        }
      }
    }
  } else {
#pragma unroll
    for (int n = 0; n < 4; n++) {
      int e = n0 + wc * 64 + n * 16 + cc;
      float bv = bias[e];
#pragma unroll
      for (int m = 0; m < 4; m++) {
        int rowb = m0 + wr * 64 + m * 16 + rq;
#pragma unroll
        for (int r = 0; r < 4; r++)
          Cout[(size_t)(rowb + r) * N + e] = acc[m][n][r] + bv;
      }
    }
  }
}

// ---------------- flash attention: per (b,h), 64 q-rows per block ----------------
// Q,K: [bh][n][64] fp16 ; Vt: [bh][64][n] fp16 ; ctx out: [b][n][1024] fp16
__global__ __launch_bounds__(256) void k_attn(const half_t* __restrict__ Qh,
                                              const half_t* __restrict__ Kh,
                                              const half_t* __restrict__ Vt,
                                              half_t* __restrict__ ctx) {
  __shared__ half_t P[4][16 * 72];
  const int lane = threadIdx.x & 63;
  const int w = threadIdx.x >> 6;
  const int qb = blockIdx.x;
  const int bh = blockIdx.y;
  const int b_ = bh >> 4, h = bh & 15;
  const int q0 = qb * 64 + w * 16;
  const int fr = lane & 15, grp = lane >> 4;

  const half_t* Qp = Qh + (size_t)bh * (1024 * 64);
  const half_t* Kp = Kh + (size_t)bh * (1024 * 64);
  const half_t* Vp = Vt + (size_t)bh * (64 * 1024);

  half8v aq[2];
#pragma unroll
  for (int c = 0; c < 2; c++) {
    aq[c] = *(const half8v*)(Qp + (size_t)(q0 + fr) * 64 + c * 32 + grp * 8);
    aq[c] = aq[c] * (_Float16)0.125f;  // 1/sqrt(64) folded into Q
  }

  float4v co[4] = {};
  float mrow[4] = {-1e30f, -1e30f, -1e30f, -1e30f};
  float ssum[4] = {};

  for (int kb = 0; kb < 1024; kb += 64) {
    float4v sacc[4] = {};
#pragma unroll
    for (int c = 0; c < 2; c++)
#pragma unroll
      for (int n = 0; n < 4; n++) {
        half8v bk = *(const half8v*)(Kp + (size_t)(kb + n * 16 + fr) * 64 + c * 32 + grp * 8);
        sacc[n] = __builtin_amdgcn_mfma_f32_16x16x32_f16(aq[c], bk, sacc[n], 0, 0, 0);
      }
    float rmax[4];
#pragma unroll
    for (int r = 0; r < 4; r++)
      rmax[r] = fmaxf(fmaxf(sacc[0][r], sacc[1][r]), fmaxf(sacc[2][r], sacc[3][r]));
#pragma unroll
    for (int msk = 1; msk <= 8; msk <<= 1)
#pragma unroll
      for (int r = 0; r < 4; r++)
        rmax[r] = fmaxf(rmax[r], __shfl_xor(rmax[r], msk, 64));
    float fac[4], rsum[4], pvv[4][4];
#pragma unroll
    for (int r = 0; r < 4; r++) {
      float mn = fmaxf(mrow[r], rmax[r]);
      fac[r] = __expf(mrow[r] - mn);
      mrow[r] = mn;
      rsum[r] = 0.f;
    }
#pragma unroll
    for (int n = 0; n < 4; n++)
#pragma unroll
      for (int r = 0; r < 4; r++) {
        pvv[n][r] = __expf(sacc[n][r] - mrow[r]);
        rsum[r] += pvv[n][r];
      }
#pragma unroll
    for (int msk = 1; msk <= 8; msk <<= 1)
#pragma unroll
      for (int r = 0; r < 4; r++) rsum[r] += __shfl_xor(rsum[r], msk, 64);
#pragma unroll
    for (int r = 0; r < 4; r++) ssum[r] = ssum[r] * fac[r] + rsum[r];
#pragma unroll
    for (int d = 0; d < 4; d++)
#pragma unroll
      for (int r = 0; r < 4; r++) co[d][r] *= fac[r];
      // P (C-layout) -> LDS -> (A-layout), private per wave, same-wave in-order DS
#pragma unroll
    for (int n = 0; n < 4; n++)
#pragma unroll
      for (int r = 0; r < 4; r++)
        P[w][(grp * 4 + r) * 72 + n * 16 + fr] = (half_t)pvv[n][r];
    asm volatile("s_waitcnt lgkmcnt(0)" ::: "memory");
#pragma unroll
    for (int c = 0; c < 2; c++) {
      half8v pa = *(const half8v*)(&P[w][fr * 72 + c * 32 + grp * 8]);
#pragma unroll
      for (int d = 0; d < 4; d++) {
        half8v bv = *(const half8v*)(Vp + (size_t)(d * 16 + fr) * 1024 + kb + c * 32 + grp * 8);
        co[d] = __builtin_amdgcn_mfma_f32_16x16x32_f16(pa, bv, co[d], 0, 0, 0);
      }
    }
  }
  float rinv[4];
#pragma unroll
  for (int r = 0; r < 4; r++) rinv[r] = 1.0f / ssum[r];
#pragma unroll
  for (int d = 0; d < 4; d++)
#pragma unroll
    for (int r = 0; r < 4; r++)
      ctx[((size_t)b_ * 1024 + q0 + grp * 4 + r) * 1024 + h * 64 + d * 16 + fr] =
          (half_t)(co[d][r] * rinv[r]);
}

extern "C" void kernel_launch(void* const* d_in, const int* in_sizes, int n_in,
                              void* d_out, int out_size, void* d_ws, size_t ws_size,
                              hipStream_t stream) {
  const float* x = (const float*)d_in[0];
  const float* Wqkv = (const float*)d_in[1];
  const float* bqkv = (const float*)d_in[2];
  const float* Wo = (const float*)d_in[3];
  const float* bo = (const float*)d_in[4];
  float* out = (float*)d_out;
  char* ws = (char*)d_ws;

  // ws layout (bytes):
  // xh/ctxh : [0, 16MiB)           8192x1024 fp16  (ctx reuses xh after QKV gemm)
  // wqkvT   : [16MiB, 22MiB)       3072x1024 fp16
  // woT     : [22MiB, 24MiB)       1024x1024 fp16
  // Qh      : [24MiB, 40MiB)       [128][1024][64] fp16
  // Kh      : [40MiB, 56MiB)
  // Vt      : [56MiB, 72MiB)       [128][64][1024] fp16
  const size_t NEED = 75497472;
  if (ws_size < NEED) return;  // cannot run correctly; fail loudly via poison output
  half_t* xh = (half_t*)(ws);
  half_t* wqkvT = (half_t*)(ws + 16777216);
  half_t* woT = (half_t*)(ws + 23068672);
  half_t* Qh = (half_t*)(ws + 25165824);
  half_t* Kh = (half_t*)(ws + 41943040);
  half_t* Vt = (half_t*)(ws + 58720256);
  half_t* ctxh = xh;

  k_cvt<<<8192, 256, 0, stream>>>(x, xh);
  k_tcvt<<<dim3(96, 32), 256, 0, stream>>>(Wqkv, wqkvT, 1024, 3072);
  k_tcvt<<<dim3(32, 32), 256, 0, stream>>>(Wo, woT, 1024, 1024);
  k_gemm<0><<<dim3(64, 24), 256, 0, stream>>>(xh, wqkvT, bqkv, nullptr, Qh, Kh, Vt,
                                              8192, 3072, 1024);
  k_attn<<<dim3(16, 128), 256, 0, stream>>>(Qh, Kh, Vt, ctxh);
  k_gemm<1><<<dim3(64, 8), 256, 0, stream>>>(ctxh, woT, bo, out, nullptr, nullptr, nullptr,
                                             8192, 1024, 1024);
}

// Round 2
// 268.195 us; speedup vs baseline: 1.3809x; 1.3809x over previous
//
#include <hip/hip_runtime.h>
#include <cstdint>
#include <cstddef>

typedef _Float16 half_t;
typedef __attribute__((ext_vector_type(4))) _Float16 half4v;
typedef __attribute__((ext_vector_type(8))) _Float16 half8v;
typedef __attribute__((ext_vector_type(4))) float float4v;

typedef __attribute__((address_space(1))) const void gv_t;
typedef __attribute__((address_space(3))) void lv_t;

__device__ __forceinline__ void lds_cp16(const void* g, void* l) {
  __builtin_amdgcn_global_load_lds((gv_t*)g, (lv_t*)l, 16, 0, 0);
}

// ---------------- convert fp32 -> fp16, vectorized x4 ----------------
__global__ __launch_bounds__(256) void k_cvt(const float* __restrict__ in,
                                             half_t* __restrict__ out) {
  int i = blockIdx.x * 256 + threadIdx.x;
  float4 v = ((const float4*)in)[i];
  half4v h = {(half_t)v.x, (half_t)v.y, (half_t)v.z, (half_t)v.w};
  ((half4v*)out)[i] = h;
}

// ---------- transpose + convert: in[R][C] fp32 -> out[C][R] fp16 ----------
__global__ __launch_bounds__(256) void k_tcvt(const float* __restrict__ in,
                                              half_t* __restrict__ out, int R, int C) {
  __shared__ float t[32][33];
  int c0 = blockIdx.x * 32, r0 = blockIdx.y * 32;
  int tc = threadIdx.x & 31, tr = threadIdx.x >> 5;  // tr 0..7
#pragma unroll
  for (int i = 0; i < 4; i++)
    t[tr + i * 8][tc] = in[(size_t)(r0 + tr + i * 8) * C + c0 + tc];
  __syncthreads();
#pragma unroll
  for (int i = 0; i < 4; i++)
    out[(size_t)(c0 + tr + i * 8) * R + r0 + tc] = (half_t)t[tc][tr + i * 8];
}

// ---------------- 128x128x32 fp16 MFMA GEMM, C = A @ Bt^T ----------------
// A: [M][K] fp16 row-major. Bt: [N][K] fp16 (i.e. B transposed).
// 1D grid with bijective XCD swizzle (requires gridDim.x % 8 == 0).
// EPI==0: QKV epilogue -> scatter Q[bh][n][hd], K[bh][n][hd], V^T[bh][hd][n], + bias
// EPI==1: fp32 out + bias
template <int EPI>
__global__ __launch_bounds__(256) void k_gemm(
    const half_t* __restrict__ A, const half_t* __restrict__ Bt,
    const float* __restrict__ bias, float* __restrict__ Cout,
    half_t* __restrict__ Qo, half_t* __restrict__ Ko, half_t* __restrict__ Vo,
    int M, int N, int K, int NB) {
  __shared__ half_t As[128 * 32];
  __shared__ half_t Bs[128 * 32];
  const int tid = threadIdx.x;
  const int lane = tid & 63;
  const int w = tid >> 6;
  // XCD-aware bijective swizzle
  const int nwg = gridDim.x;
  const int cpx = nwg >> 3;
  const int sid = (blockIdx.x & 7) * cpx + (blockIdx.x >> 3);
  const int m0 = (sid / NB) * 128;
  const int n0 = (sid % NB) * 128;
  const int wr = w >> 1, wc = w & 1;

  const int c0 = w * 2, c1 = c0 + 1;
  const int sr0 = c0 * 16 + (lane >> 2);
  const int sr1 = c1 * 16 + (lane >> 2);
  const int scol = (lane & 3) * 8;

  const half_t* Ag0 = A + (size_t)(m0 + sr0) * K + scol;
  const half_t* Ag1 = A + (size_t)(m0 + sr1) * K + scol;
  const half_t* Bg0 = Bt + (size_t)(n0 + sr0) * K + scol;
  const half_t* Bg1 = Bt + (size_t)(n0 + sr1) * K + scol;

  float4v acc[4][4] = {};

  const int fr = lane & 15;
  const int fg = lane >> 4;
  const int aoff = (wr * 64 + fr) * 32 + fg * 8;
  const int boff = (wc * 64 + fr) * 32 + fg * 8;

  for (int kt = 0; kt < K; kt += 32) {
    lds_cp16(Ag0 + kt, As + c0 * 512);
    lds_cp16(Ag1 + kt, As + c1 * 512);
    lds_cp16(Bg0 + kt, Bs + c0 * 512);
    lds_cp16(Bg1 + kt, Bs + c1 * 512);
    __syncthreads();
    half8v a[4], b[4];
#pragma unroll
    for (int m = 0; m < 4; m++) a[m] = *(const half8v*)(As + aoff + m * 512);
#pragma unroll
    for (int n = 0; n < 4; n++) b[n] = *(const half8v*)(Bs + boff + n * 512);
#pragma unroll
    for (int m = 0; m < 4; m++)
#pragma unroll
      for (int n = 0; n < 4; n++)
        acc[m][n] = __builtin_amdgcn_mfma_f32_16x16x32_f16(a[m], b[n], acc[m][n], 0, 0, 0);
    __syncthreads();
  }

  const int rq = (lane >> 4) * 4;
  const int cc = lane & 15;
  if constexpr (EPI == 0) {
#pragma unroll
    for (int n = 0; n < 4; n++) {
      int e = n0 + wc * 64 + n * 16 + cc;
      float bv = bias[e];
      int which = e >> 10, h = (e >> 6) & 15, hd = e & 63;
#pragma unroll
      for (int m = 0; m < 4; m++) {
        int rowb = m0 + wr * 64 + m * 16 + rq;
#pragma unroll
        for (int r = 0; r < 4; r++) {
          int row = rowb + r;
          int b_ = row >> 10, tok = row & 1023;
          half_t hv = (half_t)(acc[m][n][r] + bv);
          size_t bh = (size_t)(b_ * 16 + h);
          if (which == 0)
            Qo[(bh * 1024 + tok) * 64 + hd] = hv;
          else if (which == 1)
            Ko[(bh * 1024 + tok) * 64 + hd] = hv;
          else
            Vo[(bh * 64 + hd) * 1024 + tok] = hv;
        }
      }
    }
  } else {
#pragma unroll
    for (int n = 0; n < 4; n++) {
      int e = n0 + wc * 64 + n * 16 + cc;
      float bv = bias[e];
#pragma unroll
      for (int m = 0; m < 4; m++) {
        int rowb = m0 + wr * 64 + m * 16 + rq;
#pragma unroll
        for (int r = 0; r < 4; r++)
          Cout[(size_t)(rowb + r) * N + e] = acc[m][n][r] + bv;
      }
    }
  }
}

// ---------------- flash attention v2 ----------------
// Q,K: [bh][n][64] fp16 ; Vt: [bh][64][n] fp16 ; ctx out: [b][n][1024] fp16
// Block: 256 threads = 4 waves; each wave owns 32 q-rows; block = 128 q-rows.
// K/V tiles (64x64 fp16) staged in LDS (global_load_lds, XOR-swizzled via
// pre-swizzled global source), double-buffered, shared by all 4 waves.
__global__ __launch_bounds__(256) void k_attn(const half_t* __restrict__ Qh,
                                              const half_t* __restrict__ Kh,
                                              const half_t* __restrict__ Vt,
                                              half_t* __restrict__ ctx) {
  __shared__ alignas(16) half_t Ks[2][64 * 64];
  __shared__ alignas(16) half_t Vs[2][64 * 64];
  __shared__ alignas(16) half_t P[4][32 * 64];
  const int lane = threadIdx.x & 63;
  const int w = threadIdx.x >> 6;
  const int bh = blockIdx.y;
  const int b_ = bh >> 4, h = bh & 15;
  const int q0 = blockIdx.x * 128 + w * 32;
  const int fr = lane & 15, grp = lane >> 4;

  const half_t* Qp = Qh + (size_t)bh * (1024 * 64);
  const half_t* Kp = Kh + (size_t)bh * (1024 * 64);
  const half_t* Vp = Vt + (size_t)bh * (64 * 1024);

  // staging geometry: tile = 64 rows x 64 halves = 512 granules of 16B.
  // wave w, instr i in {0,1}: granule G = w*128 + i*64 + lane.
  // LDS is linear in G; global source column-granule is XOR-pre-swizzled.
  const int Ga = w * 128 + lane, Gb = Ga + 64;
  const int ra = Ga >> 3, ca = ((Ga & 7) ^ (ra & 7)) * 8;
  const int rb = Gb >> 3, cb = ((Gb & 7) ^ (rb & 7)) * 8;
  const int la = (w * 128) * 8;        // halves, wave-uniform LDS base, instr 0
  const int lb = (w * 128 + 64) * 8;   // instr 1

  // Q fragments (scale folded): aq[m][c], m = q-subtile, c = 32-wide k chunk
  half8v aq[2][2];
#pragma unroll
  for (int m = 0; m < 2; m++)
#pragma unroll
    for (int c = 0; c < 2; c++) {
      half8v t = *(const half8v*)(Qp + (size_t)(q0 + m * 16 + fr) * 64 + c * 32 + grp * 8);
      aq[m][c] = t * (_Float16)0.125f;  // 1/sqrt(64)
    }

  float4v co[2][4] = {};
  float mrow[2][4] = {{-1e30f, -1e30f, -1e30f, -1e30f}, {-1e30f, -1e30f, -1e30f, -1e30f}};
  float ssum[2][4] = {};

  // prologue: stage tile 0 into buffer 0
  lds_cp16(Kp + (size_t)ra * 64 + ca, &Ks[0][la]);
  lds_cp16(Kp + (size_t)rb * 64 + cb, &Ks[0][lb]);
  lds_cp16(Vp + (size_t)ra * 1024 + 0 + ca, &Vs[0][la]);
  lds_cp16(Vp + (size_t)rb * 1024 + 0 + cb, &Vs[0][lb]);
  __syncthreads();

  int cur = 0;
  for (int t = 0; t < 16; t++) {
    const int kb = t * 64;
    // prefetch next tile into the other buffer (loads fly during compute)
    if (t < 15) {
      const int kn = kb + 64;
      lds_cp16(Kp + (size_t)(kn + ra) * 64 + ca, &Ks[cur ^ 1][la]);
      lds_cp16(Kp + (size_t)(kn + rb) * 64 + cb, &Ks[cur ^ 1][lb]);
      lds_cp16(Vp + (size_t)ra * 1024 + kn + ca, &Vs[cur ^ 1][la]);
      lds_cp16(Vp + (size_t)rb * 1024 + kn + cb, &Vs[cur ^ 1][lb]);
    }

    // ---- QK^T: sacc[m][n], rows q = m*16 + grp*4 + r, col k = n*16 + fr ----
    float4v sacc[2][4] = {};
#pragma unroll
    for (int c = 0; c < 2; c++)
#pragma unroll
      for (int n = 0; n < 4; n++) {
        int row = n * 16 + fr;
        half8v bk = *(const half8v*)(&Ks[cur][row * 64 + (((c * 4 + grp) ^ (fr & 7)) * 8)]);
#pragma unroll
        for (int m = 0; m < 2; m++)
          sacc[m][n] = __builtin_amdgcn_mfma_f32_16x16x32_f16(aq[m][c], bk, sacc[m][n], 0, 0, 0);
      }

    // ---- online softmax + write P (swizzled granules) ----
#pragma unroll
    for (int m = 0; m < 2; m++) {
      float rmax[4];
#pragma unroll
      for (int r = 0; r < 4; r++)
        rmax[r] = fmaxf(fmaxf(sacc[m][0][r], sacc[m][1][r]),
                        fmaxf(sacc[m][2][r], sacc[m][3][r]));
#pragma unroll
      for (int msk = 1; msk <= 8; msk <<= 1)
#pragma unroll
        for (int r = 0; r < 4; r++) rmax[r] = fmaxf(rmax[r], __shfl_xor(rmax[r], msk, 64));
      float fac[4], rsum[4];
#pragma unroll
      for (int r = 0; r < 4; r++) {
        float mn = fmaxf(mrow[m][r], rmax[r]);
        fac[r] = __expf(mrow[m][r] - mn);
        mrow[m][r] = mn;
        rsum[r] = 0.f;
      }
#pragma unroll
      for (int n = 0; n < 4; n++)
#pragma unroll
        for (int r = 0; r < 4; r++) {
          float p = __expf(sacc[m][n][r] - mrow[m][r]);
          rsum[r] += p;
          // P[q][k], q = m*16+grp*4+r, k = n*16+fr; granule-XOR layout
          int q = m * 16 + grp * 4 + r;
          int off = q * 64 + (((n * 2 + (fr >> 3)) ^ (q & 7)) * 8) + (fr & 7);
          P[w][off] = (half_t)p;
        }
#pragma unroll
      for (int msk = 1; msk <= 8; msk <<= 1)
#pragma unroll
        for (int r = 0; r < 4; r++) rsum[r] += __shfl_xor(rsum[r], msk, 64);
#pragma unroll
      for (int r = 0; r < 4; r++) ssum[m][r] = ssum[m][r] * fac[r] + rsum[r];
#pragma unroll
      for (int d = 0; d < 4; d++)
#pragma unroll
        for (int r = 0; r < 4; r++) co[m][d][r] *= fac[r];
    }
    asm volatile("s_waitcnt lgkmcnt(0)" ::: "memory");

    // ---- PV: co[m][d] += P(q,k) * V(k,d) ----
#pragma unroll
    for (int c = 0; c < 2; c++) {
      half8v pa[2];
#pragma unroll
      for (int m = 0; m < 2; m++)
        pa[m] = *(const half8v*)(&P[w][(m * 16 + fr) * 64 + (((c * 4 + grp) ^ (fr & 7)) * 8)]);
#pragma unroll
      for (int d = 0; d < 4; d++) {
        half8v bv = *(const half8v*)(&Vs[cur][(d * 16 + fr) * 64 + (((c * 4 + grp) ^ (fr & 7)) * 8)]);
#pragma unroll
        for (int m = 0; m < 2; m++)
          co[m][d] = __builtin_amdgcn_mfma_f32_16x16x32_f16(pa[m], bv, co[m][d], 0, 0, 0);
      }
    }
    __syncthreads();  // drains vmcnt (next tile staged) + all waves done reading cur
    cur ^= 1;
  }

  float rinv[2][4];
#pragma unroll
  for (int m = 0; m < 2; m++)
#pragma unroll
    for (int r = 0; r < 4; r++) rinv[m][r] = 1.0f / ssum[m][r];
#pragma unroll
  for (int m = 0; m < 2; m++)
#pragma unroll
    for (int d = 0; d < 4; d++)
#pragma unroll
      for (int r = 0; r < 4; r++)
        ctx[((size_t)b_ * 1024 + q0 + m * 16 + grp * 4 + r) * 1024 + h * 64 + d * 16 + fr] =
            (half_t)(co[m][d][r] * rinv[m][r]);
}

extern "C" void kernel_launch(void* const* d_in, const int* in_sizes, int n_in,
                              void* d_out, int out_size, void* d_ws, size_t ws_size,
                              hipStream_t stream) {
  const float* x = (const float*)d_in[0];
  const float* Wqkv = (const float*)d_in[1];
  const float* bqkv = (const float*)d_in[2];
  const float* Wo = (const float*)d_in[3];
  const float* bo = (const float*)d_in[4];
  float* out = (float*)d_out;
  char* ws = (char*)d_ws;

  const size_t NEED = 75497472;
  if (ws_size < NEED) return;
  half_t* xh = (half_t*)(ws);
  half_t* wqkvT = (half_t*)(ws + 16777216);
  half_t* woT = (half_t*)(ws + 23068672);
  half_t* Qh = (half_t*)(ws + 25165824);
  half_t* Kh = (half_t*)(ws + 41943040);
  half_t* Vt = (half_t*)(ws + 58720256);
  half_t* ctxh = xh;

  k_cvt<<<8192, 256, 0, stream>>>(x, xh);
  k_tcvt<<<dim3(96, 32), 256, 0, stream>>>(Wqkv, wqkvT, 1024, 3072);
  k_tcvt<<<dim3(32, 32), 256, 0, stream>>>(Wo, woT, 1024, 1024);
  k_gemm<0><<<1536, 256, 0, stream>>>(xh, wqkvT, bqkv, nullptr, Qh, Kh, Vt,
                                      8192, 3072, 1024, 24);
  k_attn<<<dim3(8, 128), 256, 0, stream>>>(Qh, Kh, Vt, ctxh);
  k_gemm<1><<<512, 256, 0, stream>>>(ctxh, woT, bo, out, nullptr, nullptr, nullptr,
                                     8192, 1024, 1024, 8);
}

// Round 3
// 207.614 us; speedup vs baseline: 1.7838x; 1.2918x over previous
//
#include <hip/hip_runtime.h>
#include <cstdint>
#include <cstddef>

typedef _Float16 half_t;
typedef __attribute__((ext_vector_type(4))) _Float16 half4v;
typedef __attribute__((ext_vector_type(8))) _Float16 half8v;
typedef __attribute__((ext_vector_type(2))) _Float16 half2v;
typedef __attribute__((ext_vector_type(4))) float float4v;
typedef __attribute__((ext_vector_type(16))) float float16v;
typedef __attribute__((ext_vector_type(4))) unsigned uint4v;
typedef __attribute__((ext_vector_type(2))) int int2v;

typedef __attribute__((address_space(1))) const void gv_t;
typedef __attribute__((address_space(3))) void lv_t;

__device__ __forceinline__ void lds_cp16(const void* g, void* l) {
  __builtin_amdgcn_global_load_lds((gv_t*)g, (lv_t*)l, 16, 0, 0);
}

__device__ __forceinline__ unsigned pkh(float a, float b) {
  return __builtin_bit_cast(unsigned, __builtin_amdgcn_cvt_pkrtz(a, b));
}

// ---------------- convert fp32 -> fp16, vectorized x4 ----------------
__global__ __launch_bounds__(256) void k_cvt(const float* __restrict__ in,
                                             half_t* __restrict__ out) {
  int i = blockIdx.x * 256 + threadIdx.x;
  float4 v = ((const float4*)in)[i];
  half4v h = {(half_t)v.x, (half_t)v.y, (half_t)v.z, (half_t)v.w};
  ((half4v*)out)[i] = h;
}

// ---------- transpose + convert: in[R][C] fp32 -> out[C][R] fp16 ----------
__global__ __launch_bounds__(256) void k_tcvt(const float* __restrict__ in,
                                              half_t* __restrict__ out, int R, int C) {
  __shared__ float t[32][33];
  int c0 = blockIdx.x * 32, r0 = blockIdx.y * 32;
  int tc = threadIdx.x & 31, tr = threadIdx.x >> 5;  // tr 0..7
#pragma unroll
  for (int i = 0; i < 4; i++)
    t[tr + i * 8][tc] = in[(size_t)(r0 + tr + i * 8) * C + c0 + tc];
  __syncthreads();
#pragma unroll
  for (int i = 0; i < 4; i++)
    out[(size_t)(c0 + tr + i * 8) * R + r0 + tc] = (half_t)t[tc][tr + i * 8];
}

// ---------------- 128x128x32 fp16 MFMA GEMM, C = A @ Bt^T ----------------
template <int EPI>
__global__ __launch_bounds__(256) void k_gemm(
    const half_t* __restrict__ A, const half_t* __restrict__ Bt,
    const float* __restrict__ bias, float* __restrict__ Cout,
    half_t* __restrict__ Qo, half_t* __restrict__ Ko, half_t* __restrict__ Vo,
    int M, int N, int K, int NB) {
  __shared__ half_t As[128 * 32];
  __shared__ half_t Bs[128 * 32];
  const int tid = threadIdx.x;
  const int lane = tid & 63;
  const int w = tid >> 6;
  const int nwg = gridDim.x;
  const int cpx = nwg >> 3;
  const int sid = (blockIdx.x & 7) * cpx + (blockIdx.x >> 3);
  const int m0 = (sid / NB) * 128;
  const int n0 = (sid % NB) * 128;
  const int wr = w >> 1, wc = w & 1;

  const int c0 = w * 2, c1 = c0 + 1;
  const int sr0 = c0 * 16 + (lane >> 2);
  const int sr1 = c1 * 16 + (lane >> 2);
  const int scol = (lane & 3) * 8;

  const half_t* Ag0 = A + (size_t)(m0 + sr0) * K + scol;
  const half_t* Ag1 = A + (size_t)(m0 + sr1) * K + scol;
  const half_t* Bg0 = Bt + (size_t)(n0 + sr0) * K + scol;
  const half_t* Bg1 = Bt + (size_t)(n0 + sr1) * K + scol;

  float4v acc[4][4] = {};

  const int fr = lane & 15;
  const int fg = lane >> 4;
  const int aoff = (wr * 64 + fr) * 32 + fg * 8;
  const int boff = (wc * 64 + fr) * 32 + fg * 8;

  for (int kt = 0; kt < K; kt += 32) {
    lds_cp16(Ag0 + kt, As + c0 * 512);
    lds_cp16(Ag1 + kt, As + c1 * 512);
    lds_cp16(Bg0 + kt, Bs + c0 * 512);
    lds_cp16(Bg1 + kt, Bs + c1 * 512);
    __syncthreads();
    half8v a[4], b[4];
#pragma unroll
    for (int m = 0; m < 4; m++) a[m] = *(const half8v*)(As + aoff + m * 512);
#pragma unroll
    for (int n = 0; n < 4; n++) b[n] = *(const half8v*)(Bs + boff + n * 512);
#pragma unroll
    for (int m = 0; m < 4; m++)
#pragma unroll
      for (int n = 0; n < 4; n++)
        acc[m][n] = __builtin_amdgcn_mfma_f32_16x16x32_f16(a[m], b[n], acc[m][n], 0, 0, 0);
    __syncthreads();
  }

  const int rq = (lane >> 4) * 4;
  const int cc = lane & 15;
  if constexpr (EPI == 0) {
#pragma unroll
    for (int n = 0; n < 4; n++) {
      int e = n0 + wc * 64 + n * 16 + cc;
      float bv = bias[e];
      int which = e >> 10, h = (e >> 6) & 15, hd = e & 63;
#pragma unroll
      for (int m = 0; m < 4; m++) {
        int rowb = m0 + wr * 64 + m * 16 + rq;
#pragma unroll
        for (int r = 0; r < 4; r++) {
          int row = rowb + r;
          int b_ = row >> 10, tok = row & 1023;
          half_t hv = (half_t)(acc[m][n][r] + bv);
          size_t bh = (size_t)(b_ * 16 + h);
          if (which == 0)
            Qo[(bh * 1024 + tok) * 64 + hd] = hv;
          else if (which == 1)
            Ko[(bh * 1024 + tok) * 64 + hd] = hv;
          else
            Vo[(bh * 64 + hd) * 1024 + tok] = hv;
        }
      }
    }
  } else {
#pragma unroll
    for (int n = 0; n < 4; n++) {
      int e = n0 + wc * 64 + n * 16 + cc;
      float bv = bias[e];
#pragma unroll
      for (int m = 0; m < 4; m++) {
        int rowb = m0 + wr * 64 + m * 16 + rq;
#pragma unroll
        for (int r = 0; r < 4; r++)
          Cout[(size_t)(rowb + r) * N + e] = acc[m][n][r] + bv;
      }
    }
  }
}

// ---------------- flash attention v3: swapped-operand 32x32, in-register P ----
// Q,K: [bh][n][64] fp16 ; Vt: [bh][64][n] fp16 ; ctx out: [b][n][1024] fp16
// 512 threads = 8 waves; wave owns 32 q-rows (block = 256). KVBLK = 64.
// Swapped QK^T: sacc = mfma(Kfrag, Qfrag) -> C col = lane&31 = q (lane-local row
// stats). P -> PV B-frag in-register via cvt_pkrtz + permlane32_swap.
// Swapped PV: co = mfma(V^T frag, Pfrag) -> C col = q, rows = d.
__global__ __launch_bounds__(512, 4) void k_attn(const half_t* __restrict__ Qh,
                                                 const half_t* __restrict__ Kh,
                                                 const half_t* __restrict__ Vt,
                                                 half_t* __restrict__ ctx) {
  __shared__ alignas(16) half_t Ks[2][64 * 64];
  __shared__ alignas(16) half_t Vs[2][64 * 64];
  const int lane = threadIdx.x & 63;
  const int w = threadIdx.x >> 6;
  const int ql = lane & 31, hi = lane >> 5;
  // XCD-affine decode: all 4 q-blocks of a bh on one XCD (512 blocks, 8 XCDs)
  const int xcd = blockIdx.x & 7, loc = blockIdx.x >> 3;
  const int bh = xcd * 16 + (loc >> 2), qb = loc & 3;
  const int b_ = bh >> 4, h = bh & 15;
  const int q0 = qb * 256 + w * 32;

  const half_t* Qp = Qh + (size_t)bh * (1024 * 64);
  const half_t* Kp = Kh + (size_t)bh * (1024 * 64);
  const half_t* Vp = Vt + (size_t)bh * (64 * 1024);

  // Q fragments (B of swapped QK^T): col=q=ql, d = c*16 + hi*8 + j; scale 1/8
  half8v qf[4];
#pragma unroll
  for (int c = 0; c < 4; c++) {
    half8v tq = *(const half8v*)(Qp + (size_t)(q0 + ql) * 64 + c * 16 + hi * 8);
    qf[c] = tq * (_Float16)0.125f;
  }

  // staging: tile = 512 granules of 16B; granule G = w*64+lane (1 instr/wave).
  // row r = G>>3, stored col-granule = G&7 holds global granule (G&7)^(r&7).
  const int G = w * 64 + lane;
  const int rS = G >> 3;
  const int gS = (G & 7) ^ (rS & 7);

  float16v co[2] = {};
  float mr = -1e30f, ssum = 0.f;

  // prologue: stage tile 0
  lds_cp16(Kp + (size_t)rS * 64 + gS * 8, &Ks[0][w * 512]);
  lds_cp16(Vp + (size_t)rS * 1024 + 0 + gS * 8, &Vs[0][w * 512]);
  __syncthreads();

  int cur = 0;
  for (int t = 0; t < 16; t++) {
    if (t < 15) {
      const int kn = (t + 1) * 64;
      lds_cp16(Kp + (size_t)(kn + rS) * 64 + gS * 8, &Ks[cur ^ 1][w * 512]);
      lds_cp16(Vp + (size_t)rS * 1024 + kn + gS * 8, &Vs[cur ^ 1][w * 512]);
    }

    // ---- swapped QK^T: sacc[s] over k-subtiles s (32 k each) ----
    float16v sacc[2] = {};
    __builtin_amdgcn_s_setprio(1);
#pragma unroll
    for (int c = 0; c < 4; c++)
#pragma unroll
      for (int s = 0; s < 2; s++) {
        int row = s * 32 + ql;  // k-row
        half8v kf = *(const half8v*)(&Ks[cur][row * 64 + (((2 * c + hi) ^ (row & 7)) * 8)]);
        sacc[s] = __builtin_amdgcn_mfma_f32_32x32x16_f16(kf, qf[c], sacc[s], 0, 0, 0);
      }
    __builtin_amdgcn_s_setprio(0);
    // lane holds P[q=ql][k = 32s + (reg&3) + 8*(reg>>2) + 4*hi]

    // ---- lane-local online softmax (q = ql) ----
    float mx = -1e30f;
#pragma unroll
    for (int s = 0; s < 2; s++)
#pragma unroll
      for (int i = 0; i < 16; i++) mx = fmaxf(mx, sacc[s][i]);
    mx = fmaxf(mx, __shfl_xor(mx, 32, 64));
    if (mx > mr + 8.f) {  // defer-max: rescale only on real growth
      float fac = __expf(mr - mx);
      mr = mx;
      ssum *= fac;
#pragma unroll
      for (int dd = 0; dd < 2; dd++)
#pragma unroll
        for (int i = 0; i < 16; i++) co[dd][i] *= fac;
    }
    float rsum = 0.f;
#pragma unroll
    for (int s = 0; s < 2; s++)
#pragma unroll
      for (int i = 0; i < 16; i++) {
        float e = __expf(sacc[s][i] - mr);
        sacc[s][i] = e;
        rsum += e;
      }
    rsum += __shfl_xor(rsum, 32, 64);
    ssum += rsum;

    // ---- PV: per kc (16-k slice), build P B-frag in-register, 2 MFMAs ----
#pragma unroll
    for (int kc = 0; kc < 4; kc++) {
      const int s = kc >> 1, o = (kc & 1) * 8;
      unsigned dA0 = pkh(sacc[s][o + 0], sacc[s][o + 1]);
      unsigned dA1 = pkh(sacc[s][o + 2], sacc[s][o + 3]);
      unsigned dB0 = pkh(sacc[s][o + 4], sacc[s][o + 5]);
      unsigned dB1 = pkh(sacc[s][o + 6], sacc[s][o + 7]);
      int2v r0 = __builtin_amdgcn_permlane32_swap((int)dA0, (int)dB0, false, false);
      int2v r1 = __builtin_amdgcn_permlane32_swap((int)dA1, (int)dB1, false, false);
      uint4v pw = {(unsigned)r0.x, (unsigned)r1.x, (unsigned)r0.y, (unsigned)r1.y};
      half8v pf = __builtin_bit_cast(half8v, pw);
      __builtin_amdgcn_s_setprio(1);
#pragma unroll
      for (int dd = 0; dd < 2; dd++) {
        int row = dd * 32 + ql;  // d-row of V^T
        half8v vf = *(const half8v*)(&Vs[cur][row * 64 + (((2 * kc + hi) ^ (row & 7)) * 8)]);
        co[dd] = __builtin_amdgcn_mfma_f32_32x32x16_f16(vf, pf, co[dd], 0, 0, 0);
      }
      __builtin_amdgcn_s_setprio(0);
    }
    __syncthreads();  // all waves done with cur; prefetch (vmcnt) drained
    cur ^= 1;
  }

  // ---- epilogue: ctx[b][tok][h*64+d], d = 32dd + 8g + 4hi + {0..3} ----
  float rinv = 1.0f / ssum;
  half_t* outp = ctx + ((size_t)(b_ * 1024 + q0 + ql) * 1024 + h * 64);
#pragma unroll
  for (int dd = 0; dd < 2; dd++)
#pragma unroll
    for (int g = 0; g < 4; g++) {
      int d0 = dd * 32 + g * 8 + hi * 4;
      unsigned p0 = pkh(co[dd][g * 4 + 0] * rinv, co[dd][g * 4 + 1] * rinv);
      unsigned p1 = pkh(co[dd][g * 4 + 2] * rinv, co[dd][g * 4 + 3] * rinv);
      *(unsigned*)(outp + d0) = p0;
      *(unsigned*)(outp + d0 + 2) = p1;
    }
}

extern "C" void kernel_launch(void* const* d_in, const int* in_sizes, int n_in,
                              void* d_out, int out_size, void* d_ws, size_t ws_size,
                              hipStream_t stream) {
  const float* x = (const float*)d_in[0];
  const float* Wqkv = (const float*)d_in[1];
  const float* bqkv = (const float*)d_in[2];
  const float* Wo = (const float*)d_in[3];
  const float* bo = (const float*)d_in[4];
  float* out = (float*)d_out;
  char* ws = (char*)d_ws;

  const size_t NEED = 75497472;
  if (ws_size < NEED) return;
  half_t* xh = (half_t*)(ws);
  half_t* wqkvT = (half_t*)(ws + 16777216);
  half_t* woT = (half_t*)(ws + 23068672);
  half_t* Qh = (half_t*)(ws + 25165824);
  half_t* Kh = (half_t*)(ws + 41943040);
  half_t* Vt = (half_t*)(ws + 58720256);
  half_t* ctxh = xh;

  k_cvt<<<8192, 256, 0, stream>>>(x, xh);
  k_tcvt<<<dim3(96, 32), 256, 0, stream>>>(Wqkv, wqkvT, 1024, 3072);
  k_tcvt<<<dim3(32, 32), 256, 0, stream>>>(Wo, woT, 1024, 1024);
  k_gemm<0><<<1536, 256, 0, stream>>>(xh, wqkvT, bqkv, nullptr, Qh, Kh, Vt,
                                      8192, 3072, 1024, 24);
  k_attn<<<512, 512, 0, stream>>>(Qh, Kh, Vt, ctxh);
  k_gemm<1><<<512, 256, 0, stream>>>(ctxh, woT, bo, out, nullptr, nullptr, nullptr,
                                     8192, 1024, 1024, 8);
}

// Round 4
// 178.600 us; speedup vs baseline: 2.0736x; 1.1625x over previous
//
#include <hip/hip_runtime.h>
#include <cstdint>
#include <cstddef>

typedef _Float16 half_t;
typedef __attribute__((ext_vector_type(4))) _Float16 half4v;
typedef __attribute__((ext_vector_type(8))) _Float16 half8v;
typedef __attribute__((ext_vector_type(4))) float float4v;
typedef __attribute__((ext_vector_type(16))) float float16v;
typedef __attribute__((ext_vector_type(4))) unsigned uint4v;
typedef __attribute__((ext_vector_type(2))) int int2v;

typedef __attribute__((address_space(1))) const void gv_t;
typedef __attribute__((address_space(3))) void lv_t;

__device__ __forceinline__ void lds_cp16(const void* g, void* l) {
  __builtin_amdgcn_global_load_lds((gv_t*)g, (lv_t*)l, 16, 0, 0);
}

__device__ __forceinline__ unsigned pkh(float a, float b) {
  return __builtin_bit_cast(unsigned, __builtin_amdgcn_cvt_pkrtz(a, b));
}

// ---------------- convert fp32 -> fp16, vectorized x4 ----------------
__global__ __launch_bounds__(256) void k_cvt(const float* __restrict__ in,
                                             half_t* __restrict__ out) {
  int i = blockIdx.x * 256 + threadIdx.x;
  float4 v = ((const float4*)in)[i];
  half4v h = {(half_t)v.x, (half_t)v.y, (half_t)v.z, (half_t)v.w};
  ((half4v*)out)[i] = h;
}

// ---------- transpose + convert: in[R][C] fp32 -> out[C][R] fp16 ----------
__global__ __launch_bounds__(256) void k_tcvt(const float* __restrict__ in,
                                              half_t* __restrict__ out, int R, int C) {
  __shared__ float t[32][33];
  int c0 = blockIdx.x * 32, r0 = blockIdx.y * 32;
  int tc = threadIdx.x & 31, tr = threadIdx.x >> 5;  // tr 0..7
#pragma unroll
  for (int i = 0; i < 4; i++)
    t[tr + i * 8][tc] = in[(size_t)(r0 + tr + i * 8) * C + c0 + tc];
  __syncthreads();
#pragma unroll
  for (int i = 0; i < 4; i++)
    out[(size_t)(c0 + tr + i * 8) * R + r0 + tc] = (half_t)t[tc][tr + i * 8];
}

// ---------------- 128x128x32 fp16 MFMA GEMM, C = A @ Bt^T ----------------
// A: [M][K] fp16 row-major. Bt: [N][K] fp16. Requires M == 8192 (MBtot=64).
// Double-buffered LDS (2-phase pipeline), granule-XOR swizzle (pre-swizzled
// global source, linear LDS dest), L2-chunked XCD-affine block mapping.
// EPI==0: QKV epilogue -> scatter Q[bh][n][hd], K[bh][n][hd], V^T[bh][hd][n], + bias
// EPI==1: fp32 out + bias
template <int EPI>
__global__ __launch_bounds__(256) void k_gemm(
    const half_t* __restrict__ A, const half_t* __restrict__ Bt,
    const float* __restrict__ bias, float* __restrict__ Cout,
    half_t* __restrict__ Qo, half_t* __restrict__ Ko, half_t* __restrict__ Vo,
    int M, int N, int K) {
  __shared__ half_t As[2][128 * 32];
  __shared__ half_t Bs[2][128 * 32];
  const int tid = threadIdx.x;
  const int lane = tid & 63;
  const int w = tid >> 6;
  // XCD-affine, L2-chunked: 8 m-panels x 8 n-panels per chunk (~4MB working set)
  const int xcd = blockIdx.x & 7;
  const int l = blockIdx.x >> 3;
  const int nc = l >> 6, r = l & 63;
  const int m0 = (xcd * 8 + (r >> 3)) * 128;
  const int n0 = (nc * 8 + (r & 7)) * 128;
  const int wr = w >> 1, wc = w & 1;

  // staging: chunk c = 16 rows x 32 halves (64 granules of 16B), LDS linear.
  // stored col-granule cpos holds global granule cpos ^ ((row>>1)&3).
  const int c0 = w * 2, c1 = c0 + 1;
  const int srow = lane >> 2;  // 0..15 within chunk
  const int sr0 = c0 * 16 + srow;
  const int sr1 = c1 * 16 + srow;
  const int scol = ((lane & 3) ^ ((lane >> 3) & 3)) * 8;

  const half_t* Ag0 = A + (size_t)(m0 + sr0) * K + scol;
  const half_t* Ag1 = A + (size_t)(m0 + sr1) * K + scol;
  const half_t* Bg0 = Bt + (size_t)(n0 + sr0) * K + scol;
  const half_t* Bg1 = Bt + (size_t)(n0 + sr1) * K + scol;

  float4v acc[4][4] = {};

  const int fr = lane & 15;
  const int fg = lane >> 4;
  const int cswz = (fg ^ ((fr >> 1) & 3)) * 8;
  const int aoff = (wr * 64 + fr) * 32 + cswz;
  const int boff = (wc * 64 + fr) * 32 + cswz;

  // prologue: stage tile 0 into buffer 0
  lds_cp16(Ag0, &As[0][c0 * 512]);
  lds_cp16(Ag1, &As[0][c1 * 512]);
  lds_cp16(Bg0, &Bs[0][c0 * 512]);
  lds_cp16(Bg1, &Bs[0][c1 * 512]);
  __syncthreads();

  const int NT = K >> 5;
  int cur = 0;
  for (int t = 0; t < NT; t++) {
    if (t + 1 < NT) {
      const int kn = (t + 1) * 32;
      lds_cp16(Ag0 + kn, &As[cur ^ 1][c0 * 512]);
      lds_cp16(Ag1 + kn, &As[cur ^ 1][c1 * 512]);
      lds_cp16(Bg0 + kn, &Bs[cur ^ 1][c0 * 512]);
      lds_cp16(Bg1 + kn, &Bs[cur ^ 1][c1 * 512]);
    }
    half8v a[4], b[4];
#pragma unroll
    for (int m = 0; m < 4; m++) a[m] = *(const half8v*)(&As[cur][aoff + m * 512]);
#pragma unroll
    for (int n = 0; n < 4; n++) b[n] = *(const half8v*)(&Bs[cur][boff + n * 512]);
#pragma unroll
    for (int m = 0; m < 4; m++)
#pragma unroll
      for (int n = 0; n < 4; n++)
        acc[m][n] = __builtin_amdgcn_mfma_f32_16x16x32_f16(a[m], b[n], acc[m][n], 0, 0, 0);
    __syncthreads();  // drains vmcnt (prefetch landed) + all waves done with cur
    cur ^= 1;
  }

  const int rq = (lane >> 4) * 4;
  const int cc = lane & 15;
  if constexpr (EPI == 0) {
#pragma unroll
    for (int n = 0; n < 4; n++) {
      int e = n0 + wc * 64 + n * 16 + cc;
      float bv = bias[e];
      int which = e >> 10, h = (e >> 6) & 15, hd = e & 63;
#pragma unroll
      for (int m = 0; m < 4; m++) {
        int rowb = m0 + wr * 64 + m * 16 + rq;
#pragma unroll
        for (int r2 = 0; r2 < 4; r2++) {
          int row = rowb + r2;
          int b_ = row >> 10, tok = row & 1023;
          half_t hv = (half_t)(acc[m][n][r2] + bv);
          size_t bh = (size_t)(b_ * 16 + h);
          if (which == 0)
            Qo[(bh * 1024 + tok) * 64 + hd] = hv;
          else if (which == 1)
            Ko[(bh * 1024 + tok) * 64 + hd] = hv;
          else
            Vo[(bh * 64 + hd) * 1024 + tok] = hv;
        }
      }
    }
  } else {
#pragma unroll
    for (int n = 0; n < 4; n++) {
      int e = n0 + wc * 64 + n * 16 + cc;
      float bv = bias[e];
#pragma unroll
      for (int m = 0; m < 4; m++) {
        int rowb = m0 + wr * 64 + m * 16 + rq;
#pragma unroll
        for (int r2 = 0; r2 < 4; r2++)
          Cout[(size_t)(rowb + r2) * N + e] = acc[m][n][r2] + bv;
      }
    }
  }
}

// ---------------- flash attention v3: swapped-operand 32x32, in-register P ----
// Q,K: [bh][n][64] fp16 ; Vt: [bh][64][n] fp16 ; ctx out: [b][n][1024] fp16
__global__ __launch_bounds__(512, 4) void k_attn(const half_t* __restrict__ Qh,
                                                 const half_t* __restrict__ Kh,
                                                 const half_t* __restrict__ Vt,
                                                 half_t* __restrict__ ctx) {
  __shared__ alignas(16) half_t Ks[2][64 * 64];
  __shared__ alignas(16) half_t Vs[2][64 * 64];
  const int lane = threadIdx.x & 63;
  const int w = threadIdx.x >> 6;
  const int ql = lane & 31, hi = lane >> 5;
  const int xcd = blockIdx.x & 7, loc = blockIdx.x >> 3;
  const int bh = xcd * 16 + (loc >> 2), qb = loc & 3;
  const int b_ = bh >> 4, h = bh & 15;
  const int q0 = qb * 256 + w * 32;

  const half_t* Qp = Qh + (size_t)bh * (1024 * 64);
  const half_t* Kp = Kh + (size_t)bh * (1024 * 64);
  const half_t* Vp = Vt + (size_t)bh * (64 * 1024);

  half8v qf[4];
#pragma unroll
  for (int c = 0; c < 4; c++) {
    half8v tq = *(const half8v*)(Qp + (size_t)(q0 + ql) * 64 + c * 16 + hi * 8);
    qf[c] = tq * (_Float16)0.125f;
  }

  const int G = w * 64 + lane;
  const int rS = G >> 3;
  const int gS = (G & 7) ^ (rS & 7);

  float16v co[2] = {};
  float mr = -1e30f, ssum = 0.f;

  lds_cp16(Kp + (size_t)rS * 64 + gS * 8, &Ks[0][w * 512]);
  lds_cp16(Vp + (size_t)rS * 1024 + 0 + gS * 8, &Vs[0][w * 512]);
  __syncthreads();

  int cur = 0;
  for (int t = 0; t < 16; t++) {
    if (t < 15) {
      const int kn = (t + 1) * 64;
      lds_cp16(Kp + (size_t)(kn + rS) * 64 + gS * 8, &Ks[cur ^ 1][w * 512]);
      lds_cp16(Vp + (size_t)rS * 1024 + kn + gS * 8, &Vs[cur ^ 1][w * 512]);
    }

    float16v sacc[2] = {};
    __builtin_amdgcn_s_setprio(1);
#pragma unroll
    for (int c = 0; c < 4; c++)
#pragma unroll
      for (int s = 0; s < 2; s++) {
        int row = s * 32 + ql;
        half8v kf = *(const half8v*)(&Ks[cur][row * 64 + (((2 * c + hi) ^ (row & 7)) * 8)]);
        sacc[s] = __builtin_amdgcn_mfma_f32_32x32x16_f16(kf, qf[c], sacc[s], 0, 0, 0);
      }
    __builtin_amdgcn_s_setprio(0);

    float mx = -1e30f;
#pragma unroll
    for (int s = 0; s < 2; s++)
#pragma unroll
      for (int i = 0; i < 16; i++) mx = fmaxf(mx, sacc[s][i]);
    mx = fmaxf(mx, __shfl_xor(mx, 32, 64));
    if (mx > mr + 8.f) {
      float fac = __expf(mr - mx);
      mr = mx;
      ssum *= fac;
#pragma unroll
      for (int dd = 0; dd < 2; dd++)
#pragma unroll
        for (int i = 0; i < 16; i++) co[dd][i] *= fac;
    }
    float rsum = 0.f;
#pragma unroll
    for (int s = 0; s < 2; s++)
#pragma unroll
      for (int i = 0; i < 16; i++) {
        float e = __expf(sacc[s][i] - mr);
        sacc[s][i] = e;
        rsum += e;
      }
    rsum += __shfl_xor(rsum, 32, 64);
    ssum += rsum;

#pragma unroll
    for (int kc = 0; kc < 4; kc++) {
      const int s = kc >> 1, o = (kc & 1) * 8;
      unsigned dA0 = pkh(sacc[s][o + 0], sacc[s][o + 1]);
      unsigned dA1 = pkh(sacc[s][o + 2], sacc[s][o + 3]);
      unsigned dB0 = pkh(sacc[s][o + 4], sacc[s][o + 5]);
      unsigned dB1 = pkh(sacc[s][o + 6], sacc[s][o + 7]);
      int2v r0 = __builtin_amdgcn_permlane32_swap((int)dA0, (int)dB0, false, false);
      int2v r1 = __builtin_amdgcn_permlane32_swap((int)dA1, (int)dB1, false, false);
      uint4v pw = {(unsigned)r0.x, (unsigned)r1.x, (unsigned)r0.y, (unsigned)r1.y};
      half8v pf = __builtin_bit_cast(half8v, pw);
      __builtin_amdgcn_s_setprio(1);
#pragma unroll
      for (int dd = 0; dd < 2; dd++) {
        int row = dd * 32 + ql;
        half8v vf = *(const half8v*)(&Vs[cur][row * 64 + (((2 * kc + hi) ^ (row & 7)) * 8)]);
        co[dd] = __builtin_amdgcn_mfma_f32_32x32x16_f16(vf, pf, co[dd], 0, 0, 0);
      }
      __builtin_amdgcn_s_setprio(0);
    }
    __syncthreads();
    cur ^= 1;
  }

  float rinv = 1.0f / ssum;
  half_t* outp = ctx + ((size_t)(b_ * 1024 + q0 + ql) * 1024 + h * 64);
#pragma unroll
  for (int dd = 0; dd < 2; dd++)
#pragma unroll
    for (int g = 0; g < 4; g++) {
      int d0 = dd * 32 + g * 8 + hi * 4;
      unsigned p0 = pkh(co[dd][g * 4 + 0] * rinv, co[dd][g * 4 + 1] * rinv);
      unsigned p1 = pkh(co[dd][g * 4 + 2] * rinv, co[dd][g * 4 + 3] * rinv);
      *(unsigned*)(outp + d0) = p0;
      *(unsigned*)(outp + d0 + 2) = p1;
    }
}

extern "C" void kernel_launch(void* const* d_in, const int* in_sizes, int n_in,
                              void* d_out, int out_size, void* d_ws, size_t ws_size,
                              hipStream_t stream) {
  const float* x = (const float*)d_in[0];
  const float* Wqkv = (const float*)d_in[1];
  const float* bqkv = (const float*)d_in[2];
  const float* Wo = (const float*)d_in[3];
  const float* bo = (const float*)d_in[4];
  float* out = (float*)d_out;
  char* ws = (char*)d_ws;

  const size_t NEED = 75497472;
  if (ws_size < NEED) return;
  half_t* xh = (half_t*)(ws);
  half_t* wqkvT = (half_t*)(ws + 16777216);
  half_t* woT = (half_t*)(ws + 23068672);
  half_t* Qh = (half_t*)(ws + 25165824);
  half_t* Kh = (half_t*)(ws + 41943040);
  half_t* Vt = (half_t*)(ws + 58720256);
  half_t* ctxh = xh;

  k_cvt<<<8192, 256, 0, stream>>>(x, xh);
  k_tcvt<<<dim3(96, 32), 256, 0, stream>>>(Wqkv, wqkvT, 1024, 3072);
  k_tcvt<<<dim3(32, 32), 256, 0, stream>>>(Wo, woT, 1024, 1024);
  k_gemm<0><<<1536, 256, 0, stream>>>(xh, wqkvT, bqkv, nullptr, Qh, Kh, Vt,
                                      8192, 3072, 1024);
  k_attn<<<512, 512, 0, stream>>>(Qh, Kh, Vt, ctxh);
  k_gemm<1><<<512, 256, 0, stream>>>(ctxh, woT, bo, out, nullptr, nullptr, nullptr,
                                     8192, 1024, 1024);
}